// Round 13
// baseline (27.971 us; speedup 1.0000x reference)
//
#include <hip/hip_runtime.h>

#define B 32
#define L 512
#define D 768
#define M 24
#define P (M * (M - 1))   // 552

typedef float f32x2 __attribute__((ext_vector_type(2)));

// 3072 blocks x 384 threads. Block = (row-half rh, mention g, column-half).
// All rh=0 blocks (rows 0..11 of each mention's 23) dispatch before rh=1
// blocks (rows 12..22): with ~1280 blocks resident, the rh=1 cohort starts
// while rh=0 blocks are still draining stores -> gathers overlap writes.
// Within a block: threads rp=t>=192 gather even/odd span rows (deduped),
// LDS combine, then <=12 regular coalesced f32x2 stores per thread.
__global__ void __launch_bounds__(384, 8)
fused_kernel(const float* __restrict__ seq,   // B,L,D
             const int*   __restrict__ head,  // B,L
             const int*   __restrict__ em,    // B,M,2
             float*       __restrict__ out)   // B*P*1536 rel | B*P*5 pairs
{
    __shared__ f32x2 pool[2][192];   // 3 KB

    int blk   = blockIdx.x;          // 0..3071
    int rh    = blk >= 1536;         // row-half cohort (rh=0 dispatches first)
    int base  = blk - rh * 1536;
    int g     = base >> 1;           // mention id 0..767
    int chalf = base & 1;            // column half
    int b = g / M, m = g - b * M;
    int t  = threadIdx.x;            // 0..383
    int rp = (t >= 192);             // even/odd gather parity + store role
    int c  = t - rp * 192;           // 0..191
    int col = chalf * 192 + c;       // global f32x2 column 0..383

    const float* seqb  = seq  + (size_t)b * L * D;
    const int*   headb = head + b * L;
    const int*   emb   = em   + b * M * 2;

    int s = emb[2 * m];
    int e = emb[2 * m + 1];
    int len = e - s;                 // 1..15
    int cnt = (len - rp + 1) >> 1;   // rows this parity accumulates (<=8)

    // deduplicated parallel gather (full span -> full mean, both cohorts)
    int hidx[8];
    #pragma unroll
    for (int r = 0; r < 8; ++r) {
        int l = s + rp + 2 * r;
        l = (l < e) ? l : s;         // clamp -> unconditional
        hidx[r] = headb[l];
    }
    f32x2 vv[8];
    #pragma unroll
    for (int r = 0; r < 8; ++r)
        vv[r] = ((const f32x2*)(seqb + (size_t)hidx[r] * D))[col];
    f32x2 acc = (f32x2)(0.f);
    #pragma unroll
    for (int r = 0; r < 8; ++r)
        acc += (r < cnt) ? vv[r] : (f32x2)(0.f);

    pool[rp][c] = acc;
    __syncthreads();
    f32x2 v = (pool[0][c] + pool[1][c]) * (1.0f / (float)len);

    // fan-out writes: this block covers row positions [lo,hi) of the 23
    int lo = rh ? 12 : 0;
    int hi = rh ? 23 : 12;

    f32x2* outg = (f32x2*)out;       // rel rows: 768 f32x2 each
    size_t rowbase = (size_t)b * P;

    if (rp == 0) {
        // OBJ half of rows m*23 + r, r in [lo,hi), granule offset col
        size_t q = (rowbase + (size_t)m * 23 + lo) * 768 + col;
        int n = hi - lo;             // 12 or 11, block-uniform
        #pragma unroll
        for (int r = 0; r < 12; ++r) {
            if (r < n) {
                outg[q] = v;
                q += 768;
            }
        }
        if (!rh && chalf == 0 && c < 23) {
            int rr = c;
            int j = (rr < m) ? rr : rr + 1;
            float* o = out + (size_t)B * P * 2 * D
                     + (rowbase + (size_t)m * 23 + rr) * 5;
            o[0] = (float)b;
            o[1] = (float)s;
            o[2] = (float)e;
            o[3] = (float)emb[2 * j];
            o[4] = (float)emb[2 * j + 1];
        }
    } else {
        // SUB half: mention is j == m; enumerate i != m, position k in [lo,hi)
        #pragma unroll
        for (int i = 0; i < M; ++i) {
            if (i == m) continue;
            int k = i - (i > m);     // position of i in the 23-list
            if (k < lo || k >= hi) continue;
            int rr = (m < i) ? m : m - 1;
            size_t row = rowbase + (size_t)i * 23 + rr;
            outg[row * 768 + 384 + col] = v;
        }
    }
}

extern "C" void kernel_launch(void* const* d_in, const int* in_sizes, int n_in,
                              void* d_out, int out_size, void* d_ws, size_t ws_size,
                              hipStream_t stream) {
    const float* seq  = (const float*)d_in[0];
    const int*   head = (const int*)d_in[1];
    const int*   em   = (const int*)d_in[2];
    float* out = (float*)d_out;

    fused_kernel<<<2 * B * M * 2, 384, 0, stream>>>(seq, head, em, out);  // 3072 blocks
}